// Round 7
// baseline (615.183 us; speedup 1.0000x reference)
//
#include <hip/hip_runtime.h>
#include <cstddef>
#include <cstdint>

// Problem constants (fixed by setup_inputs)
constexpr int B_SEG   = 4;
constexpr int N_C     = 4096;    // coarse pts per batch
constexpr int M_F     = 16384;   // fine pts per batch
constexpr int CIN     = 384;
constexpr int COUT    = 192;
constexpr int MT      = B_SEG * N_C;
constexpr int MF      = B_SEG * M_F;
constexpr float LN_EPS = 1e-5f;

constexpr int G2   = 20;             // 2D cell grid (x,y); z NOT subdivided
constexpr int NCOL = G2 * G2;        // 400 columns
constexpr int CAP  = 1536;           // max staged src pts per block

typedef __bf16 bf16x8 __attribute__((ext_vector_type(8)));
typedef __bf16 bf16x4 __attribute__((ext_vector_type(4)));
typedef float  f32x4  __attribute__((ext_vector_type(4)));

__device__ __forceinline__ int cellc(float v) {
  return min(G2 - 1, max(0, (int)(v * (float)G2)));
}

// ---------------------------------------------------------------------------
// K0: transpose+convert weights to bf16 [n][k] layout.
// ---------------------------------------------------------------------------
__global__ __launch_bounds__(256) void k0_prep(
    const float* __restrict__ w2, const float* __restrict__ w1,
    __bf16* __restrict__ wt2, __bf16* __restrict__ wt1)
{
  int e = blockIdx.x * 256 + threadIdx.x;
  if (e < CIN * COUT) {
    int k = e / COUT, n = e % COUT;
    wt2[(size_t)n * CIN + k] = (__bf16)w2[e];
  }
  e -= CIN * COUT;
  if (e >= 0 && e < COUT * COUT) {
    int k = e / COUT, n = e % COUT;
    wt1[(size_t)n * COUT + k] = (__bf16)w1[e];
  }
}

// ---------------------------------------------------------------------------
// K2s: counting-sort each batch's SRC points into 400 (x,y)-columns.
// 4 blocks, one per batch. psort = {x,y,z,bitcast(j)}, cstart[401]/batch.
// ---------------------------------------------------------------------------
__global__ __launch_bounds__(256) void k2s_sort(
    const float* __restrict__ xyz, float4* __restrict__ psort,
    int* __restrict__ cstart)
{
  __shared__ int hist[512];
  __shared__ int wtot[4];
  const int tid = threadIdx.x;
  const int b   = blockIdx.x;
  hist[tid] = 0; hist[tid + 256] = 0;
  __syncthreads();

  float px[16], py[16], pz[16];
  int   pc[16];
  const float* src = xyz + (size_t)b * N_C * 3;
#pragma unroll
  for (int k = 0; k < 16; ++k) {
    int j = tid + 256 * k;
    float x = src[3 * j], y = src[3 * j + 1], z = src[3 * j + 2];
    int c = cellc(x) * G2 + cellc(y);
    px[k] = x; py[k] = y; pz[k] = z; pc[k] = c;
    atomicAdd(&hist[c], 1);
  }
  __syncthreads();

  int l0 = hist[tid * 2], l1 = hist[tid * 2 + 1], s = l0 + l1;
  const int lane = tid & 63, wv = tid >> 6;
  int incl = s;
#pragma unroll
  for (int off = 1; off < 64; off <<= 1) {
    int n = __shfl_up(incl, off);
    if (lane >= off) incl += n;
  }
  if (lane == 63) wtot[wv] = incl;
  __syncthreads();
  int wbase = 0;
  for (int w = 0; w < 4; ++w) if (w < wv) wbase += wtot[w];
  int b0 = wbase + incl - s, b1 = b0 + l0;
  if (tid * 2     < NCOL + 1) cstart[b * (NCOL + 1) + tid * 2]     = b0;
  if (tid * 2 + 1 < NCOL + 1) cstart[b * (NCOL + 1) + tid * 2 + 1] = b1;
  __syncthreads();
  hist[tid * 2] = b0; hist[tid * 2 + 1] = b1;
  __syncthreads();
#pragma unroll
  for (int k = 0; k < 16; ++k) {
    int pos = atomicAdd(&hist[pc[k]], 1);
    psort[(size_t)b * N_C + pos] =
        make_float4(px[k], py[k], pz[k], __int_as_float(tid + 256 * k));
  }
}

// ---------------------------------------------------------------------------
// DST sort pipeline (parallel): zero -> hist -> prefix -> scatter.
// ---------------------------------------------------------------------------
__global__ __launch_bounds__(256) void k2z_zero(int* __restrict__ p, int n)
{
  int i = blockIdx.x * 256 + threadIdx.x;
  if (i < n) p[i] = 0;
}

__global__ __launch_bounds__(256) void k2h_hist(
    const float* __restrict__ sxyz, int* __restrict__ dhist)
{
  for (int p = blockIdx.x * 256 + threadIdx.x; p < MF; p += 16384) {
    int b = p >> 14;
    int c = cellc(sxyz[3 * p]) * G2 + cellc(sxyz[3 * p + 1]);
    atomicAdd(&dhist[b * NCOL + c], 1);
  }
}

__global__ __launch_bounds__(256) void k2p_prefix(
    const int* __restrict__ dhist, int* __restrict__ dcur)
{
  __shared__ int wtot[4];
  const int tid = threadIdx.x;
  const int b   = blockIdx.x;
  int i0 = tid * 2, i1 = tid * 2 + 1;
  int l0 = (i0 < NCOL) ? dhist[b * NCOL + i0] : 0;
  int l1 = (i1 < NCOL) ? dhist[b * NCOL + i1] : 0;
  int s = l0 + l1;
  const int lane = tid & 63, wv = tid >> 6;
  int incl = s;
#pragma unroll
  for (int off = 1; off < 64; off <<= 1) {
    int n = __shfl_up(incl, off);
    if (lane >= off) incl += n;
  }
  if (lane == 63) wtot[wv] = incl;
  __syncthreads();
  int wbase = 0;
  for (int w = 0; w < 4; ++w) if (w < wv) wbase += wtot[w];
  int b0 = wbase + incl - s;
  if (i0 < NCOL) dcur[b * NCOL + i0] = b0;
  if (i1 < NCOL) dcur[b * NCOL + i1] = b0 + l0;
}

__global__ __launch_bounds__(256) void k2c_scatter(
    const float* __restrict__ sxyz, int* __restrict__ dcur,
    float4* __restrict__ dsort)
{
  for (int p = blockIdx.x * 256 + threadIdx.x; p < MF; p += 16384) {
    int b = p >> 14;
    float x = sxyz[3 * p], y = sxyz[3 * p + 1], z = sxyz[3 * p + 2];
    int c = cellc(x) * G2 + cellc(y);
    int pos = atomicAdd(&dcur[b * NCOL + c], 1);
    dsort[(size_t)b * M_F + pos] =
        make_float4(x, y, z, __int_as_float(p - b * M_F));
  }
}

// ---------------------------------------------------------------------------
// K2: exact 3-NN. Block = 64 cell-sorted dst x 4 segments (grid 1024 ->
// 16 waves/CU). Block stages the union column-box (dst cols +/-2, full z;
// per-x one contiguous sorted run) into LDS (~300 pts), then each thread
// runs a UNIFORM unrolled scan of its quarter (wave-broadcast LDS reads,
// compile-time-friendly bounds) — R2's efficient loop shape at ~1/50 the
// trip count. Margin >= 2 cells guarantees exactness; rare failures
// (~1e-5) rescan the whole batch from global. Reference f32 rounding;
// (d2, orig_j) lexicographic insert == stable top_k tie-break.
// ---------------------------------------------------------------------------
__global__ __launch_bounds__(256) void k2_knn(
    const float4* __restrict__ psort, const int* __restrict__ cstart,
    const float4* __restrict__ dsort, int* __restrict__ knn_i,
    float* __restrict__ knn_w)
{
  __shared__ float4 S[CAP + 4];          // ~24.6 KB
  __shared__ float  pD[4][64][3];        // 3 KB
  __shared__ int    pJ[4][64][3];        // 3 KB
  __shared__ int    chS[G2], chL[G2], chO[G2];
  __shared__ int    shT[2];
  const int tid = threadIdx.x;
  const int blk = blockIdx.x;
  const int b   = blk >> 8;              // 256 blocks per batch
  const int q   = blk & 255;

  const float4 dq = dsort[(size_t)b * M_F + q * 64 + (tid & 63)];
  const float px = dq.x, py = dq.y, pz = dq.z;
  const int olocal = __float_as_int(dq.w);
  const int cx = cellc(px), cy = cellc(py);

  // block-uniform box: each wave holds all 64 dst -> wave reduce suffices
  int xlo = cx, xhi = cx, ylo = cy, yhi = cy;
#pragma unroll
  for (int off = 1; off < 64; off <<= 1) {
    xlo = min(xlo, __shfl_xor(xlo, off));
    xhi = max(xhi, __shfl_xor(xhi, off));
    ylo = min(ylo, __shfl_xor(ylo, off));
    yhi = max(yhi, __shfl_xor(yhi, off));
  }
  const int bxlo = __builtin_amdgcn_readfirstlane(max(xlo - 2, 0));
  const int bxhi = __builtin_amdgcn_readfirstlane(min(xhi + 2, G2 - 1));
  const int bylo = __builtin_amdgcn_readfirstlane(max(ylo - 2, 0));
  const int byhi = __builtin_amdgcn_readfirstlane(min(yhi + 2, G2 - 1));
  const int nx = bxhi - bxlo + 1;

  if (tid < nx) {
    int s = cstart[b * (NCOL + 1) + (bxlo + tid) * G2 + bylo];
    int e = cstart[b * (NCOL + 1) + (bxlo + tid) * G2 + byhi + 1];
    chS[tid] = s; chL[tid] = e - s;
  }
  __syncthreads();
  if (tid == 0) {
    int off = 0;
    for (int i = 0; i < nx; ++i) { chO[i] = off; off += chL[i]; }
    shT[0] = (off > CAP) ? 0 : off;      // overflow -> everyone falls back
    shT[1] = (off > CAP) ? 0 : nx;
  }
  __syncthreads();
  const int T = shT[0], nst = shT[1];
  for (int i = 0; i < nst; ++i) {
    int s = chS[i], o = chO[i], L = chL[i];
    for (int t = tid; t < L; t += 256)
      S[o + t] = psort[(size_t)b * N_C + s + t];
  }
  const int T4 = (T + 3) & ~3;
  if (tid < T4 - T)
    S[T + tid] = make_float4(3e30f, 3e30f, 3e30f, __int_as_float(0x7ffffffe));
  __syncthreads();

  // uniform scan: wave w scans quarter w (k uniform across the wave)
  const int seg = tid >> 6, dl = tid & 63;
  const int qlen = T4 >> 2;
  float t0 = 1e30f, t1 = 1e30f, t2 = 1e30f;
  int   j0 = 0x7fffffff, j1 = 0x7fffffff, j2 = 0x7fffffff;
  {
    const int ks = seg * qlen, ke = ks + qlen;
#pragma unroll 4
    for (int k = ks; k < ke; ++k) {
      float4 sp = S[k];
      float dx = __fsub_rn(px, sp.x);
      float dy = __fsub_rn(py, sp.y);
      float dz = __fsub_rn(pz, sp.z);
      float d2 = __fadd_rn(__fadd_rn(__fmul_rn(dx, dx), __fmul_rn(dy, dy)),
                           __fmul_rn(dz, dz));
      int j = __float_as_int(sp.w);
      bool lt2 = (d2 < t2) || (d2 == t2 && j < j2);
      if (lt2) {
        bool lt1 = (d2 < t1) || (d2 == t1 && j < j1);
        if (lt1) {
          t2 = t1; j2 = j1;
          bool lt0 = (d2 < t0) || (d2 == t0 && j < j0);
          if (lt0) { t1 = t0; j1 = j0; t0 = d2; j0 = j; }
          else     { t1 = d2; j1 = j; }
        } else { t2 = d2; j2 = j; }
      }
    }
  }
  pD[seg][dl][0] = t0; pD[seg][dl][1] = t1; pD[seg][dl][2] = t2;
  pJ[seg][dl][0] = j0; pJ[seg][dl][1] = j1; pJ[seg][dl][2] = j2;
  __syncthreads();

  if (tid < 64) {
    float m0 = 1e30f, m1 = 1e30f, m2 = 1e30f;
    int   n0 = 0x7fffffff, n1 = 0x7fffffff, n2 = 0x7fffffff;
#pragma unroll
    for (int s2 = 0; s2 < 4; ++s2)
#pragma unroll
      for (int k = 0; k < 3; ++k) {
        float d = pD[s2][tid][k]; int j = pJ[s2][tid][k];
        bool lt2 = (d < m2) || (d == m2 && j < n2);
        if (lt2) {
          bool lt1 = (d < m1) || (d == m1 && j < n1);
          if (lt1) {
            m2 = m1; n2 = n1;
            bool lt0 = (d < m0) || (d == m0 && j < n0);
            if (lt0) { m1 = m0; n1 = n0; m0 = d; n0 = j; }
            else     { m1 = d; n1 = j; }
          } else { m2 = d; n2 = j; }
        }
      }
    // exactness margin vs box xy-boundary (z fully covered)
    const float hc = 1.0f / (float)G2;
    float mg = 1e30f;
    if (bxlo > 0)      mg = fminf(mg, px - (float)bxlo * hc);
    if (bxhi < G2 - 1) mg = fminf(mg, (float)(bxhi + 1) * hc - px);
    if (bylo > 0)      mg = fminf(mg, py - (float)bylo * hc);
    if (byhi < G2 - 1) mg = fminf(mg, (float)(byhi + 1) * hc - py);
    float ma = mg - 1e-5f;
    bool need = !(m2 < ma * ma);
    if (__any(need)) {
      if (need) {   // complete fresh scan of the batch (rare)
        m0 = 1e30f; m1 = 1e30f; m2 = 1e30f;
        n0 = 0x7fffffff; n1 = 0x7fffffff; n2 = 0x7fffffff;
        const float4* pb = psort + (size_t)b * N_C;
        for (int k = 0; k < N_C; ++k) {
          float4 sp = pb[k];
          float dx = __fsub_rn(px, sp.x);
          float dy = __fsub_rn(py, sp.y);
          float dz = __fsub_rn(pz, sp.z);
          float d2 = __fadd_rn(__fadd_rn(__fmul_rn(dx, dx), __fmul_rn(dy, dy)),
                               __fmul_rn(dz, dz));
          int j = __float_as_int(sp.w);
          bool lt2 = (d2 < m2) || (d2 == m2 && j < n2);
          if (lt2) {
            bool lt1 = (d2 < m1) || (d2 == m1 && j < n1);
            if (lt1) {
              m2 = m1; n2 = n1;
              bool lt0 = (d2 < m0) || (d2 == m0 && j < n0);
              if (lt0) { m1 = m0; n1 = n0; m0 = d2; n0 = j; }
              else     { m1 = d2; n1 = j; }
            } else { m2 = d2; n2 = j; }
          }
        }
      }
    }
    float d0 = sqrtf(m0), d1 = sqrtf(m1), d2s = sqrtf(m2);
    float r0 = 1.f / (d0 + 1e-8f);
    float r1 = 1.f / (d1 + 1e-8f);
    float r2 = 1.f / (d2s + 1e-8f);
    float inv = 1.f / (r0 + r1 + r2);
    const size_t dstg = (size_t)b * M_F + olocal;
    knn_i[dstg * 3 + 0] = b * N_C + n0;
    knn_i[dstg * 3 + 1] = b * N_C + n1;
    knn_i[dstg * 3 + 2] = b * N_C + n2;
    knn_w[dstg * 3 + 0] = r0 * inv;
    knn_w[dstg * 3 + 1] = r1 * inv;
    knn_w[dstg * 3 + 2] = r2 * inv;
  }
}

// ---------------------------------------------------------------------------
// K1: h = LN(feats) @ w2 + b2   [16384 x 384] x [384 x 192], h in bf16.
// 32 rows/block (grid 512); each wave: 2 A-frags share each B-load.
// ---------------------------------------------------------------------------
__global__ __launch_bounds__(256) void k1_ln_gemm(
    const float* __restrict__ feats, const float* __restrict__ ln_g,
    const float* __restrict__ ln_b, const __bf16* __restrict__ wt2,
    const float* __restrict__ b2, __bf16* __restrict__ h)
{
  __shared__ __bf16 As[32][CIN + 8];     // 25 KB
  const int tid = threadIdx.x;
  const int blk = blockIdx.x;

  {
    const int r = tid >> 3, qq = tid & 7;   // 8 threads/row, 12 float4 each
    const float* frow = feats + (size_t)(blk * 32 + r) * CIN;
    float4 v[12];
    float sum = 0.f, sumsq = 0.f;
#pragma unroll
    for (int i = 0; i < 12; ++i) {
      float4 t = *(const float4*)(frow + (qq + 8 * i) * 4);
      v[i] = t;
      sum   += (t.x + t.y) + (t.z + t.w);
      sumsq += (t.x * t.x + t.y * t.y) + (t.z * t.z + t.w * t.w);
    }
    sum += __shfl_xor(sum, 1); sumsq += __shfl_xor(sumsq, 1);
    sum += __shfl_xor(sum, 2); sumsq += __shfl_xor(sumsq, 2);
    sum += __shfl_xor(sum, 4); sumsq += __shfl_xor(sumsq, 4);
    float mean = sum * (1.f / CIN);
    float var  = sumsq * (1.f / CIN) - mean * mean;
    if (var < 0.f) var = 0.f;
    float rs = rsqrtf(var + LN_EPS);
#pragma unroll
    for (int i = 0; i < 12; ++i) {
      float4 g4 = *(const float4*)(ln_g + (qq + 8 * i) * 4);
      float4 b4 = *(const float4*)(ln_b + (qq + 8 * i) * 4);
      bf16x4 o;
      o[0] = (__bf16)((v[i].x - mean) * rs * g4.x + b4.x);
      o[1] = (__bf16)((v[i].y - mean) * rs * g4.y + b4.y);
      o[2] = (__bf16)((v[i].z - mean) * rs * g4.z + b4.z);
      o[3] = (__bf16)((v[i].w - mean) * rs * g4.w + b4.w);
      *(bf16x4*)&As[r][(qq + 8 * i) * 4] = o;
    }
  }
  __syncthreads();

  const int w = tid >> 6, lane = tid & 63, m = lane & 15, half = lane >> 4;
  f32x4 acc[3][2];
#pragma unroll
  for (int t = 0; t < 3; ++t)
#pragma unroll
    for (int rh = 0; rh < 2; ++rh) acc[t][rh] = (f32x4){0.f, 0.f, 0.f, 0.f};

  const __bf16* A0 = &As[m][half * 8];
  const __bf16* A1 = &As[m + 16][half * 8];
#pragma unroll
  for (int ch = 0; ch < 12; ++ch) {
    bf16x8 a0 = *(const bf16x8*)(A0 + ch * 32);
    bf16x8 a1 = *(const bf16x8*)(A1 + ch * 32);
#pragma unroll
    for (int t = 0; t < 3; ++t) {
      const __bf16* bp = wt2 + (size_t)(16 * (w * 3 + t) + m) * CIN +
                         half * 8 + ch * 32;
      bf16x8 b = *(const bf16x8*)bp;
      acc[t][0] = __builtin_amdgcn_mfma_f32_16x16x32_bf16(a0, b, acc[t][0], 0, 0, 0);
      acc[t][1] = __builtin_amdgcn_mfma_f32_16x16x32_bf16(a1, b, acc[t][1], 0, 0, 0);
    }
  }

#pragma unroll
  for (int t = 0; t < 3; ++t) {
    int col = 16 * (w * 3 + t) + m;
    float bv = b2[col];
#pragma unroll
    for (int rh = 0; rh < 2; ++rh) {
      int r0 = blk * 32 + rh * 16 + half * 4;
#pragma unroll
      for (int reg = 0; reg < 4; ++reg)
        h[(size_t)(r0 + reg) * COUT + col] = (__bf16)(acc[t][rh][reg] + bv);
    }
  }
}

// ---------------------------------------------------------------------------
// K3: out = LN(support_feats) @ w1 + b1 + interp(h)   [65536 x 192]
// 32 rows/block (grid 2048); bf16 h gather in epilogue.
// ---------------------------------------------------------------------------
__global__ __launch_bounds__(256) void k3_ln_gemm_interp(
    const float* __restrict__ sfeats, const float* __restrict__ ln_g,
    const float* __restrict__ ln_b, const __bf16* __restrict__ wt1,
    const float* __restrict__ b1, const __bf16* __restrict__ h,
    const int* __restrict__ knn_i, const float* __restrict__ knn_w,
    float* __restrict__ out)
{
  __shared__ __bf16 As[32][COUT + 8];    // 12.5 KB
  const int tid = threadIdx.x;
  const int blk = blockIdx.x;

  {
    const int r = tid >> 3, qq = tid & 7;   // 8 threads/row, 6 float4 each
    const float* frow = sfeats + (size_t)(blk * 32 + r) * COUT;
    float4 v[6];
    float sum = 0.f, sumsq = 0.f;
#pragma unroll
    for (int i = 0; i < 6; ++i) {
      float4 t = *(const float4*)(frow + (qq + 8 * i) * 4);
      v[i] = t;
      sum   += (t.x + t.y) + (t.z + t.w);
      sumsq += (t.x * t.x + t.y * t.y) + (t.z * t.z + t.w * t.w);
    }
    sum += __shfl_xor(sum, 1); sumsq += __shfl_xor(sumsq, 1);
    sum += __shfl_xor(sum, 2); sumsq += __shfl_xor(sumsq, 2);
    sum += __shfl_xor(sum, 4); sumsq += __shfl_xor(sumsq, 4);
    float mean = sum * (1.f / COUT);
    float var  = sumsq * (1.f / COUT) - mean * mean;
    if (var < 0.f) var = 0.f;
    float rs = rsqrtf(var + LN_EPS);
#pragma unroll
    for (int i = 0; i < 6; ++i) {
      float4 g4 = *(const float4*)(ln_g + (qq + 8 * i) * 4);
      float4 b4 = *(const float4*)(ln_b + (qq + 8 * i) * 4);
      bf16x4 o;
      o[0] = (__bf16)((v[i].x - mean) * rs * g4.x + b4.x);
      o[1] = (__bf16)((v[i].y - mean) * rs * g4.y + b4.y);
      o[2] = (__bf16)((v[i].z - mean) * rs * g4.z + b4.z);
      o[3] = (__bf16)((v[i].w - mean) * rs * g4.w + b4.w);
      *(bf16x4*)&As[r][(qq + 8 * i) * 4] = o;
    }
  }
  __syncthreads();

  const int w = tid >> 6, lane = tid & 63, m = lane & 15, half = lane >> 4;
  f32x4 acc[3][2];
#pragma unroll
  for (int t = 0; t < 3; ++t)
#pragma unroll
    for (int rh = 0; rh < 2; ++rh) acc[t][rh] = (f32x4){0.f, 0.f, 0.f, 0.f};

  const __bf16* A0 = &As[m][half * 8];
  const __bf16* A1 = &As[m + 16][half * 8];
#pragma unroll
  for (int ch = 0; ch < 6; ++ch) {
    bf16x8 a0 = *(const bf16x8*)(A0 + ch * 32);
    bf16x8 a1 = *(const bf16x8*)(A1 + ch * 32);
#pragma unroll
    for (int t = 0; t < 3; ++t) {
      const __bf16* bp = wt1 + (size_t)(16 * (w * 3 + t) + m) * COUT +
                         half * 8 + ch * 32;
      bf16x8 b = *(const bf16x8*)bp;
      acc[t][0] = __builtin_amdgcn_mfma_f32_16x16x32_bf16(a0, b, acc[t][0], 0, 0, 0);
      acc[t][1] = __builtin_amdgcn_mfma_f32_16x16x32_bf16(a1, b, acc[t][1], 0, 0, 0);
    }
  }

#pragma unroll
  for (int rh = 0; rh < 2; ++rh) {
#pragma unroll
    for (int reg = 0; reg < 4; ++reg) {
      const int R = blk * 32 + rh * 16 + half * 4 + reg;
      int   i0 = knn_i[(size_t)R * 3 + 0];
      int   i1 = knn_i[(size_t)R * 3 + 1];
      int   i2 = knn_i[(size_t)R * 3 + 2];
      float w0 = knn_w[(size_t)R * 3 + 0];
      float w1v = knn_w[(size_t)R * 3 + 1];
      float w2v = knn_w[(size_t)R * 3 + 2];
      const __bf16* h0 = h + (size_t)i0 * COUT;
      const __bf16* h1 = h + (size_t)i1 * COUT;
      const __bf16* h2 = h + (size_t)i2 * COUT;
      float* orow = out + (size_t)R * COUT;
#pragma unroll
      for (int t = 0; t < 3; ++t) {
        int col = 16 * (w * 3 + t) + m;
        orow[col] = acc[t][rh][reg] + b1[col] + w0 * (float)h0[col] +
                    w1v * (float)h1[col] + w2v * (float)h2[col];
      }
    }
  }
}

// ---------------------------------------------------------------------------
// K4: passthrough outputs
// ---------------------------------------------------------------------------
__global__ __launch_bounds__(256) void k4_tail(
    const float* __restrict__ sxyz, const int* __restrict__ soff,
    float* __restrict__ out_tail)
{
  const int t = blockIdx.x * 256 + threadIdx.x;
  if (t < MF * 3) out_tail[t] = sxyz[t];
  if (t < B_SEG) out_tail[MF * 3 + t] = (float)soff[t];
}

// ---------------------------------------------------------------------------
extern "C" void kernel_launch(void* const* d_in, const int* in_sizes, int n_in,
                              void* d_out, int out_size, void* d_ws, size_t ws_size,
                              hipStream_t stream)
{
  const float* feats  = (const float*)d_in[0];
  const float* xyz    = (const float*)d_in[1];
  const float* sxyz   = (const float*)d_in[2];
  const float* sfeats = (const float*)d_in[3];
  const int*   soff   = (const int*)d_in[5];
  const float* ln1_g  = (const float*)d_in[6];
  const float* ln1_b  = (const float*)d_in[7];
  const float* w1     = (const float*)d_in[8];
  const float* b1     = (const float*)d_in[9];
  const float* ln2_g  = (const float*)d_in[10];
  const float* ln2_b  = (const float*)d_in[11];
  const float* w2     = (const float*)d_in[12];
  const float* b2     = (const float*)d_in[13];
  float* out = (float*)d_out;

  // workspace layout (16B-aligned)
  __bf16* h      = (__bf16*)d_ws;                      // 6.3 MB
  int*    knn_i  = (int*)(h + (size_t)MT * COUT);
  float*  knn_w  = (float*)(knn_i + (size_t)MF * 3);
  float4* psort  = (float4*)(knn_w + (size_t)MF * 3);  // 256 KB
  float4* dsort  = psort + (size_t)B_SEG * N_C;        // 1 MB
  int*    cstart = (int*)(dsort + (size_t)B_SEG * M_F);// 4*401
  int*    dhist  = cstart + B_SEG * (NCOL + 1);        // 4*400
  int*    dcur   = dhist + B_SEG * NCOL;               // 4*400
  __bf16* wt2    = (__bf16*)(dcur + B_SEG * NCOL + 4);
  __bf16* wt1    = wt2 + (size_t)COUT * CIN;

  k0_prep<<<432, 256, 0, stream>>>(w2, w1, wt2, wt1);
  k2z_zero<<<7, 256, 0, stream>>>(dhist, B_SEG * NCOL);
  k2s_sort<<<B_SEG, 256, 0, stream>>>(xyz, psort, cstart);
  k2h_hist<<<64, 256, 0, stream>>>(sxyz, dhist);
  k2p_prefix<<<B_SEG, 256, 0, stream>>>(dhist, dcur);
  k2c_scatter<<<64, 256, 0, stream>>>(sxyz, dcur, dsort);
  k1_ln_gemm<<<MT / 32, 256, 0, stream>>>(feats, ln2_g, ln2_b, wt2, b2, h);
  k2_knn<<<MF / 64, 256, 0, stream>>>(psort, cstart, dsort, knn_i, knn_w);
  k3_ln_gemm_interp<<<MF / 32, 256, 0, stream>>>(sfeats, ln1_g, ln1_b, wt1, b1,
                                                 h, knn_i, knn_w, out);
  k4_tail<<<(MF * 3) / 256, 256, 0, stream>>>(sxyz, soff, out + (size_t)MF * COUT);
}